// Round 7
// baseline (202.408 us; speedup 1.0000x reference)
//
#include <hip/hip_runtime.h>

// CommNet forward, fp32. B=512, M=32, H=256, NAG=8, NACT=16.
// R7: R6's DMA pipeline + fused hid path. k_linF = full K=512 (Wc then Wr
// tiles, dbuf) + bias + tanh + hid store + xh transpose in ONE kernel:
// removes the 1MB memset, 2.1M global atomics, and the k_fin pass.
// Lessons kept: gl_lds dest = wave-uniform base + lane*size, chunk = 256
// floats (R5's c*512 bug); no launch_bounds min-wave cap (R2 spill); no
// compiler-scheduled register streaming (R3/R4 serialization).

constexpr int Bn = 512, Mn = 32, NAGn = 8, Hn = 256, NACTn = 16;
constexpr int On = Hn * NAGn;  // 2048
constexpr int En = 32;         // padded slots/model
constexpr int EW = 8;          // examples per wave (j-octet)

__device__ __forceinline__ void gl_lds16(const float* g, float* l) {
  __builtin_amdgcn_global_load_lds(
      (const __attribute__((address_space(1))) void*)g,
      (__attribute__((address_space(3))) void*)l, 16, 0, 0);
}

// ws: list32 @0 (4KB) | xcat @4096: [m][512][32] = 2MB | xh @4096+2MB: [m][256][32] = 1MB
// (xh must NOT alias xcat: k_linF blocks of one model stage xcat at different
//  times than sibling blocks write xh.)

// -------- kernel 1: padded per-model slot list --------
__global__ __launch_bounds__(512) void k_group(const int* __restrict__ ids,
                                               int* __restrict__ list32) {
  __shared__ int scnt[Mn];
  int t = threadIdx.x;
  if (t < Mn) scnt[t] = 0;
  list32[t] = -1;
  list32[t + 512] = -1;
  __syncthreads();
  int m = ids[t];
  int pos = atomicAdd(&scnt[m], 1);
  if (pos < En) list32[m * En + pos] = t;
}

// -------- kernel 2: xcat[m][k][j]; k<256 = agent-summed comm_in, k>=256 = prev_hid
__global__ __launch_bounds__(256) void k_pack(
    const float* __restrict__ comm_in, const float* __restrict__ prev_hid,
    const int* __restrict__ list32, float* __restrict__ xcat) {
  int m = blockIdx.x, half = blockIdx.y;
  int tid = threadIdx.x;
  __shared__ float buf[En][Hn + 1];
  __shared__ int lst[En];
  if (tid < En) lst[tid] = list32[m * En + tid];
  __syncthreads();
  if (half == 0) {
    for (int j = 0; j < En; j++) {
      int e = lst[j];
      float s = 0.f;
      if (e >= 0) {
        const float* cp = comm_in + (size_t)e * NAGn * Hn + tid;
#pragma unroll
        for (int a = 0; a < NAGn; a++) s += cp[a * Hn];
      }
      buf[j][tid] = s;
    }
  } else {
    for (int j = 0; j < En; j++) {
      int e = lst[j];
      buf[j][tid] = (e >= 0) ? prev_hid[e * Hn + tid] : 0.f;
    }
  }
  __syncthreads();
  int j = tid & 31, kr = tid >> 5;
  float* xm = xcat + ((size_t)m * 512 + half * Hn) * En;
  for (int k0 = 0; k0 < Hn; k0 += 8) {
    int k = k0 + kr;
    xm[(size_t)k * En + j] = buf[j][k];
  }
}

// -------- kernel 3 (fused): hid = tanh(xsum@Wc + ph@Wr + bc + br + lut + eb);
//          also packs xh[m][col][j]. grid (2 ct[128col], 32 m) = 64 blocks.
//          16 dbuf tiles: t<8 from Wc, t>=8 from Wr. No atomics, no memset.
__global__ __launch_bounds__(256) void k_linF(
    const float* __restrict__ Wc, const float* __restrict__ Wr,
    const float* __restrict__ xcat, const float* __restrict__ bc,
    const float* __restrict__ br, const int* __restrict__ inp,
    const float* __restrict__ lut, const float* __restrict__ enc_bias,
    const int* __restrict__ list32, float* __restrict__ hid,
    float* __restrict__ xh) {
  int ct = blockIdx.x, m = blockIdx.y;
  if (list32[m * En] < 0) return;
  int tid = threadIdx.x, w = tid >> 6, lane = tid & 63;
  __shared__ alignas(16) float xbuf[512 * En];      // 64 KB (full K=512 x slice)
  __shared__ alignas(16) float wbuf[2][32 * 128];   // 32 KB

  const float* xsrc = xcat + (size_t)m * 512 * En;
#pragma unroll
  for (int q = 0; q < 16; q++) {  // 64 chunks of 1KB
    int c = w * 16 + q;
    gl_lds16(xsrc + c * 256 + lane * 4, xbuf + c * 256);
  }
  const float* wcs = Wc + (size_t)m * Hn * Hn + ct * 128;
  const float* wrs = Wr + (size_t)m * Hn * Hn + ct * 128;
#pragma unroll
  for (int q = 0; q < 4; q++) {  // tile 0 (Wc rows 0..31); chunk = 2 rows = 256 floats
    int c = w * 4 + q;
    int row = c * 2 + (lane >> 5);
    gl_lds16(wcs + (size_t)row * Hn + (lane & 31) * 4, wbuf[0] + c * 256);
  }
  bool act = list32[m * En + w * EW] >= 0;
  float2 acc[EW];
#pragma unroll
  for (int j = 0; j < EW; j++) acc[j] = make_float2(0.f, 0.f);
  __syncthreads();

  for (int t = 0; t < 16; t++) {
    if (t < 15) {
      int tn = t + 1;
      const float* src = (tn < 8) ? (wcs + (size_t)tn * 32 * Hn)
                                  : (wrs + (size_t)(tn - 8) * 32 * Hn);
#pragma unroll
      for (int q = 0; q < 4; q++) {
        int c = w * 4 + q;
        int row = c * 2 + (lane >> 5);
        gl_lds16(src + (size_t)row * Hn + (lane & 31) * 4, wbuf[tn & 1] + c * 256);
      }
    }
    if (act) {
      const float* wb = wbuf[t & 1] + lane * 2;
      const float* xb = xbuf + (size_t)(t * 32) * En + w * EW;
#pragma unroll 8
      for (int k = 0; k < 32; k++) {
        float2 wv = *(const float2*)(wb + k * 128);
        float4 xa = *(const float4*)(xb + k * En);
        float4 xc = *(const float4*)(xb + k * En + 4);
        acc[0].x += xa.x * wv.x; acc[0].y += xa.x * wv.y;
        acc[1].x += xa.y * wv.x; acc[1].y += xa.y * wv.y;
        acc[2].x += xa.z * wv.x; acc[2].y += xa.z * wv.y;
        acc[3].x += xa.w * wv.x; acc[3].y += xa.w * wv.y;
        acc[4].x += xc.x * wv.x; acc[4].y += xc.x * wv.y;
        acc[5].x += xc.y * wv.x; acc[5].y += xc.y * wv.y;
        acc[6].x += xc.z * wv.x; acc[6].y += xc.z * wv.y;
        acc[7].x += xc.w * wv.x; acc[7].y += xc.w * wv.y;
      }
    }
    __syncthreads();
  }

  // epilogue: bias + tanh -> hid; stage hb[j][col'] (pad 133) for xh transpose.
  // wbuf is free after the final barrier; hb needs 32*133*4 = 17KB < 32KB.
  float* hb = (float*)wbuf;
  int col = ct * 128 + lane * 2;
  float2 bcv = *(const float2*)(bc + (size_t)m * Hn + col);
  float2 brv = *(const float2*)(br + (size_t)m * Hn + col);
  float2 ebv = *(const float2*)(enc_bias + col);
#pragma unroll
  for (int j = 0; j < EW; j++) {
    int jj = w * EW + j;
    float h0 = 0.f, h1 = 0.f;
    if (act) {
      int e = list32[m * En + jj];
      if (e >= 0) {
        int tok = inp[e];
        float2 lv = *(const float2*)(lut + (size_t)tok * Hn + col);
        h0 = tanhf(acc[j].x + bcv.x + brv.x + ebv.x + lv.x);
        h1 = tanhf(acc[j].y + bcv.y + brv.y + ebv.y + lv.y);
        *(float2*)(hid + (size_t)e * Hn + col) = make_float2(h0, h1);
      }
    }
    hb[jj * 133 + lane * 2]     = h0;  // padded slots stay 0 for k_out
    hb[jj * 133 + lane * 2 + 1] = h1;
  }
  __syncthreads();
  int j2 = tid & 31, r = tid >> 5;
  for (int i = 0; i < 16; i++) {
    int row = i * 8 + r;
    xh[((size_t)m * Hn + ct * 128 + row) * En + j2] = hb[j2 * 133 + row];
  }
}

// -------- kernel 4: comm_out = (hid @ Wo + bo) / 7, DMA-pipelined ----------
// grid (16 x 128-col tiles, 32 m) = 512 blocks. Wo tiles [32k][128c] dbuf.
__global__ __launch_bounds__(256) void k_out(
    const float* __restrict__ Wo, const float* __restrict__ xh,
    const float* __restrict__ bo, const int* __restrict__ list32,
    float* __restrict__ comm_out) {
  int ct = blockIdx.x, m = blockIdx.y;
  if (list32[m * En] < 0) return;
  int tid = threadIdx.x, w = tid >> 6, lane = tid & 63;
  __shared__ alignas(16) float xbuf[Hn * En];        // 32 KB
  __shared__ alignas(16) float wbuf[2][32 * 128];    // 32 KB

  const float* xsrc = xh + (size_t)m * Hn * En;
#pragma unroll
  for (int q = 0; q < 8; q++) {  // 32 chunks of 1KB
    int c = w * 8 + q;
    gl_lds16(xsrc + c * 256 + lane * 4, xbuf + c * 256);
  }
  const float* wsrc = Wo + (size_t)m * Hn * On + ct * 128;
#pragma unroll
  for (int q = 0; q < 4; q++) {  // tile 0; chunk = 2 rows = 256 floats
    int c = w * 4 + q;
    int row = c * 2 + (lane >> 5);
    gl_lds16(wsrc + (size_t)row * On + (lane & 31) * 4, wbuf[0] + c * 256);
  }
  bool act = list32[m * En + w * EW] >= 0;
  float2 acc[EW];
#pragma unroll
  for (int j = 0; j < EW; j++) acc[j] = make_float2(0.f, 0.f);
  __syncthreads();

  for (int t = 0; t < 8; t++) {
    if (t < 7) {
      const float* ws2 = wsrc + (size_t)(t + 1) * 32 * On;
#pragma unroll
      for (int q = 0; q < 4; q++) {
        int c = w * 4 + q;
        int row = c * 2 + (lane >> 5);
        gl_lds16(ws2 + (size_t)row * On + (lane & 31) * 4, wbuf[(t + 1) & 1] + c * 256);
      }
    }
    if (act) {
      const float* wb = wbuf[t & 1] + lane * 2;
      const float* xb = xbuf + (size_t)(t * 32) * En + w * EW;
#pragma unroll 8
      for (int k = 0; k < 32; k++) {
        float2 wv = *(const float2*)(wb + k * 128);
        float4 xa = *(const float4*)(xb + k * En);
        float4 xc = *(const float4*)(xb + k * En + 4);
        acc[0].x += xa.x * wv.x; acc[0].y += xa.x * wv.y;
        acc[1].x += xa.y * wv.x; acc[1].y += xa.y * wv.y;
        acc[2].x += xa.z * wv.x; acc[2].y += xa.z * wv.y;
        acc[3].x += xa.w * wv.x; acc[3].y += xa.w * wv.y;
        acc[4].x += xc.x * wv.x; acc[4].y += xc.x * wv.y;
        acc[5].x += xc.y * wv.x; acc[5].y += xc.y * wv.y;
        acc[6].x += xc.z * wv.x; acc[6].y += xc.z * wv.y;
        acc[7].x += xc.w * wv.x; acc[7].y += xc.w * wv.y;
      }
    }
    __syncthreads();
  }
  if (act) {
    float2 bv = *(const float2*)(bo + (size_t)m * On + ct * 128 + lane * 2);
    const float inv = 1.f / 7.f;
#pragma unroll
    for (int jj = 0; jj < EW; jj++) {
      int e = list32[m * En + w * EW + jj];
      if (e < 0) continue;
      float2 o;
      o.x = (acc[jj].x + bv.x) * inv;
      o.y = (acc[jj].y + bv.y) * inv;
      *(float2*)(comm_out + (size_t)e * On + ct * 128 + lane * 2) = o;
    }
  }
}

// -------- kernel 5: action softmax + baseline, 1 wave / example --------
__global__ __launch_bounds__(64) void k_act(
    const float* __restrict__ hid, const float* __restrict__ Wa,
    const float* __restrict__ ba, const float* __restrict__ Wb,
    const float* __restrict__ bb, const int* __restrict__ ids,
    float* __restrict__ aprob, float* __restrict__ bl) {
  int b = blockIdx.x;
  int m = ids[b];
  int l = threadIdx.x;
  int o = l & 15;
  int kk = l >> 4;

  const float* wap = Wa + (size_t)m * Hn * NACTn + l;
  const float* hbase = hid + (size_t)b * Hn;
  float al = 0.f;
  for (int w16 = 0; w16 < 4; w16++) {
    float wv[16], hv[16];
#pragma unroll
    for (int il = 0; il < 16; il++) wv[il] = wap[(w16 * 16 + il) * 64];
#pragma unroll
    for (int il = 0; il < 16; il++) hv[il] = hbase[w16 * 64 + il * 4 + kk];
#pragma unroll
    for (int il = 0; il < 16; il++) al += wv[il] * hv[il];
  }
  al += __shfl_xor(al, 16);
  al += __shfl_xor(al, 32);
  al += ba[m * NACTn + o];

  float mx = al;
  mx = fmaxf(mx, __shfl_xor(mx, 1));
  mx = fmaxf(mx, __shfl_xor(mx, 2));
  mx = fmaxf(mx, __shfl_xor(mx, 4));
  mx = fmaxf(mx, __shfl_xor(mx, 8));
  float ex = expf(al - mx);
  float sm = ex;
  sm += __shfl_xor(sm, 1);
  sm += __shfl_xor(sm, 2);
  sm += __shfl_xor(sm, 4);
  sm += __shfl_xor(sm, 8);
  if (l < 16) aprob[b * NACTn + l] = ex / sm;

  float pb = 0.f;
  const float* wbp = Wb + (size_t)m * Hn;
  {
    float wv[4], hv[4];
#pragma unroll
    for (int k = 0; k < 4; k++) { wv[k] = wbp[l + k * 64]; hv[k] = hbase[l + k * 64]; }
#pragma unroll
    for (int k = 0; k < 4; k++) pb += wv[k] * hv[k];
  }
  pb += __shfl_xor(pb, 1);
  pb += __shfl_xor(pb, 2);
  pb += __shfl_xor(pb, 4);
  pb += __shfl_xor(pb, 8);
  pb += __shfl_xor(pb, 16);
  pb += __shfl_xor(pb, 32);
  if (l == 0) bl[b] = pb + bb[m];
}

extern "C" void kernel_launch(void* const* d_in, const int* in_sizes, int n_in,
                              void* d_out, int out_size, void* d_ws, size_t ws_size,
                              hipStream_t stream) {
  const float* comm_in  = (const float*)d_in[0];
  const int*   inp      = (const int*)d_in[1];
  const float* prev_hid = (const float*)d_in[2];
  const int*   ids      = (const int*)d_in[4];
  const float* Wc = (const float*)d_in[5];
  const float* bc = (const float*)d_in[6];
  const float* Wr = (const float*)d_in[7];
  const float* br = (const float*)d_in[8];
  const float* Wa = (const float*)d_in[9];
  const float* ba = (const float*)d_in[10];
  const float* Wb = (const float*)d_in[11];
  const float* bb = (const float*)d_in[12];
  const float* Wo = (const float*)d_in[13];
  const float* bo = (const float*)d_in[14];
  const float* lut      = (const float*)d_in[15];
  const float* enc_bias = (const float*)d_in[16];

  float* out      = (float*)d_out;
  float* aprob    = out;                     // [512,16]
  float* bl       = out + Bn * NACTn;        // [512]
  float* hid      = out + Bn * NACTn + Bn;   // [512,256]
  float* comm_out = hid + Bn * Hn;           // [512,2048]

  char* ws = (char*)d_ws;
  int*   list32 = (int*)ws;                       // 4 KB
  float* xcat   = (float*)(ws + 4096);            // [32][512][32] = 2 MB
  float* xh     = (float*)(ws + 4096 + 2097152);  // [32][256][32] = 1 MB (no aliasing)

  k_group<<<1, 512, 0, stream>>>(ids, list32);
  k_pack<<<dim3(Mn, 2), 256, 0, stream>>>(comm_in, prev_hid, list32, xcat);
  k_linF<<<dim3(2, Mn), 256, 0, stream>>>(Wc, Wr, xcat, bc, br, inp, lut,
                                          enc_bias, list32, hid, xh);
  k_out<<<dim3(16, Mn), 256, 0, stream>>>(Wo, xh, bo, list32, comm_out);
  k_act<<<Bn, 64, 0, stream>>>(hid, Wa, ba, Wb, bb, ids, aprob, bl);
}

// Round 8
// 190.977 us; speedup vs baseline: 1.0599x; 1.0599x over previous
//
#include <hip/hip_runtime.h>

// CommNet forward, fp32. B=512, M=32, H=256, NAG=8, NACT=16.
// R8: hid phase = 256-block K-split (R6 structure) with partial-sum buffers
// (no memset, no atomics); k_out tiles shrunk to 16 rows -> 48KB LDS ->
// 3 blocks/CU (R7 lesson: the DMA+barrier pipeline needs >=2-3 co-resident
// blocks/CU to hide the vmcnt(0) drain; 64-block fusion collapsed to 250GB/s).
// Kept lessons: gl_lds dest = wave-uniform base + lane*16B, chunk=256 floats;
// no launch_bounds min-wave cap (R2 spill); no register streaming (R3/R4).

constexpr int Bn = 512, Mn = 32, NAGn = 8, Hn = 256, NACTn = 16;
constexpr int On = Hn * NAGn;  // 2048
constexpr int En = 32;         // padded slots/model
constexpr int EW = 8;          // examples per wave (j-octet)

__device__ __forceinline__ void gl_lds16(const float* g, float* l) {
  __builtin_amdgcn_global_load_lds(
      (const __attribute__((address_space(1))) void*)g,
      (__attribute__((address_space(3))) void*)l, 16, 0, 0);
}

// ws: list32 @0 (4KB) | xcat @4096: [m][512][32] = 2MB
//     xh @4096+2MB: [m][256][32] = 1MB | acc4 @4096+3MB: [kc][m][32][256] = 4MB

// -------- kernel 1: padded per-model slot list --------
__global__ __launch_bounds__(512) void k_group(const int* __restrict__ ids,
                                               int* __restrict__ list32) {
  __shared__ int scnt[Mn];
  int t = threadIdx.x;
  if (t < Mn) scnt[t] = 0;
  list32[t] = -1;
  list32[t + 512] = -1;
  __syncthreads();
  int m = ids[t];
  int pos = atomicAdd(&scnt[m], 1);
  if (pos < En) list32[m * En + pos] = t;
}

// -------- kernel 2: xcat[m][k][j]; k<256 = agent-summed comm_in, k>=256 = prev_hid
__global__ __launch_bounds__(256) void k_pack(
    const float* __restrict__ comm_in, const float* __restrict__ prev_hid,
    const int* __restrict__ list32, float* __restrict__ xcat) {
  int m = blockIdx.x, half = blockIdx.y;
  int tid = threadIdx.x;
  __shared__ float buf[En][Hn + 1];
  __shared__ int lst[En];
  if (tid < En) lst[tid] = list32[m * En + tid];
  __syncthreads();
  if (half == 0) {
    for (int j = 0; j < En; j++) {
      int e = lst[j];
      float s = 0.f;
      if (e >= 0) {
        const float* cp = comm_in + (size_t)e * NAGn * Hn + tid;
#pragma unroll
        for (int a = 0; a < NAGn; a++) s += cp[a * Hn];
      }
      buf[j][tid] = s;
    }
  } else {
    for (int j = 0; j < En; j++) {
      int e = lst[j];
      buf[j][tid] = (e >= 0) ? prev_hid[e * Hn + tid] : 0.f;
    }
  }
  __syncthreads();
  int j = tid & 31, kr = tid >> 5;
  float* xm = xcat + ((size_t)m * 512 + half * Hn) * En;
  for (int k0 = 0; k0 < Hn; k0 += 8) {
    int k = k0 + kr;
    xm[(size_t)k * En + j] = buf[j][k];
  }
}

// -------- kernel 3: acc4[kc] = xcat-chunk @ {Wc,Wr}-chunk (plain stores) ----
// grid (2 ct[128col], 4 kc[128k of concat 512], 32 m) = 256 blocks; 48KB LDS.
__global__ __launch_bounds__(256) void k_lin(
    const float* __restrict__ Wc, const float* __restrict__ Wr,
    const float* __restrict__ xcat, const int* __restrict__ list32,
    float* __restrict__ acc4) {
  int ct = blockIdx.x, kc = blockIdx.y, m = blockIdx.z;
  if (list32[m * En] < 0) return;
  int tid = threadIdx.x, w = tid >> 6, lane = tid & 63;
  __shared__ alignas(16) float xbuf[128 * En];       // 16 KB
  __shared__ alignas(16) float wbuf[2][32 * 128];    // 32 KB

  const float* W = (kc < 2) ? (Wc + ((size_t)m * Hn + kc * 128) * Hn)
                            : (Wr + ((size_t)m * Hn + (kc - 2) * 128) * Hn);
  const float* wsrc = W + ct * 128;
  const float* xsrc = xcat + ((size_t)m * 512 + kc * 128) * En;
#pragma unroll
  for (int q = 0; q < 4; q++) {  // x slice: 16 chunks of 1KB
    int c = w * 4 + q;
    gl_lds16(xsrc + c * 256 + lane * 4, xbuf + c * 256);
  }
#pragma unroll
  for (int q = 0; q < 4; q++) {  // W tile 0: rows 0..31; chunk = 2 rows = 256 fl
    int c = w * 4 + q;
    int row = c * 2 + (lane >> 5);
    gl_lds16(wsrc + (size_t)row * Hn + (lane & 31) * 4, wbuf[0] + c * 256);
  }
  bool act = list32[m * En + w * EW] >= 0;
  float2 acc[EW];
#pragma unroll
  for (int j = 0; j < EW; j++) acc[j] = make_float2(0.f, 0.f);
  __syncthreads();

  for (int t = 0; t < 4; t++) {
    if (t < 3) {
      const float* ws2 = wsrc + (size_t)(t + 1) * 32 * Hn;
#pragma unroll
      for (int q = 0; q < 4; q++) {
        int c = w * 4 + q;
        int row = c * 2 + (lane >> 5);
        gl_lds16(ws2 + (size_t)row * Hn + (lane & 31) * 4, wbuf[(t + 1) & 1] + c * 256);
      }
    }
    if (act) {
      const float* wb = wbuf[t & 1] + lane * 2;
      const float* xb = xbuf + (size_t)(t * 32) * En + w * EW;
#pragma unroll 8
      for (int k = 0; k < 32; k++) {
        float2 wv = *(const float2*)(wb + k * 128);
        float4 xa = *(const float4*)(xb + k * En);
        float4 xc = *(const float4*)(xb + k * En + 4);
        acc[0].x += xa.x * wv.x; acc[0].y += xa.x * wv.y;
        acc[1].x += xa.y * wv.x; acc[1].y += xa.y * wv.y;
        acc[2].x += xa.z * wv.x; acc[2].y += xa.z * wv.y;
        acc[3].x += xa.w * wv.x; acc[3].y += xa.w * wv.y;
        acc[4].x += xc.x * wv.x; acc[4].y += xc.x * wv.y;
        acc[5].x += xc.y * wv.x; acc[5].y += xc.y * wv.y;
        acc[6].x += xc.z * wv.x; acc[6].y += xc.z * wv.y;
        acc[7].x += xc.w * wv.x; acc[7].y += xc.w * wv.y;
      }
    }
    __syncthreads();
  }
  if (act) {
    float* ap = acc4 + (((size_t)kc * Mn + m) * En + w * EW) * Hn + ct * 128 + lane * 2;
#pragma unroll
    for (int j = 0; j < EW; j++)
      *(float2*)(ap + (size_t)j * Hn) = acc[j];
  }
}

// -------- kernel 4: hid = tanh(sum4(acc4) + bc + br + lut + eb); pack xh ----
__global__ __launch_bounds__(256) void k_fin(
    const float* __restrict__ acc4, const float* __restrict__ bc,
    const float* __restrict__ br, const int* __restrict__ inp,
    const float* __restrict__ lut, const float* __restrict__ enc_bias,
    const int* __restrict__ list32, float* __restrict__ hid,
    float* __restrict__ xh) {
  int m = blockIdx.x, cs4 = blockIdx.y;  // 64-col strip
  int tid = threadIdx.x, lane = tid & 63, jw = tid >> 6;
  int col = cs4 * 64 + lane;
  __shared__ float hb[En][65];
  __shared__ int lst[En];
  if (tid < En) lst[tid] = list32[m * En + tid];
  __syncthreads();
  float bsum = bc[m * Hn + col] + br[m * Hn + col] + enc_bias[col];
  for (int jj = 0; jj < EW; jj++) {
    int j = jw * EW + jj;
    int e = lst[j];
    float h = 0.f;
    if (e >= 0) {
      int tok = inp[e];
      float t = bsum + lut[(size_t)tok * Hn + col];
#pragma unroll
      for (int kc = 0; kc < 4; kc++)
        t += acc4[(((size_t)kc * Mn + m) * En + j) * Hn + col];
      h = tanhf(t);
      hid[(size_t)e * Hn + col] = h;
    }
    hb[j][lane] = h;  // padded slots 0 for k_out
  }
  __syncthreads();
  int j2 = tid & 31, kr = tid >> 5;
  for (int k0 = 0; k0 < 64; k0 += 8) {
    int kl = k0 + kr;
    xh[((size_t)m * Hn + cs4 * 64 + kl) * En + j2] = hb[j2][kl];
  }
}

// -------- kernel 5: comm_out = (hid @ Wo + bo) / 7, DMA-pipelined ----------
// grid (16 x 128-col tiles, 32 m) = 512 blocks. 16-row dbuf tiles; 48KB LDS
// -> 3 blocks/CU.
__global__ __launch_bounds__(256) void k_out(
    const float* __restrict__ Wo, const float* __restrict__ xh,
    const float* __restrict__ bo, const int* __restrict__ list32,
    float* __restrict__ comm_out) {
  int ct = blockIdx.x, m = blockIdx.y;
  if (list32[m * En] < 0) return;
  int tid = threadIdx.x, w = tid >> 6, lane = tid & 63;
  __shared__ alignas(16) float xbuf[Hn * En];        // 32 KB
  __shared__ alignas(16) float wbuf[2][16 * 128];    // 16 KB

  const float* xsrc = xh + (size_t)m * Hn * En;
#pragma unroll
  for (int q = 0; q < 8; q++) {  // 32 chunks of 1KB
    int c = w * 8 + q;
    gl_lds16(xsrc + c * 256 + lane * 4, xbuf + c * 256);
  }
  const float* wsrc = Wo + (size_t)m * Hn * On + ct * 128;
#pragma unroll
  for (int q = 0; q < 2; q++) {  // tile 0: rows 0..15; 8 chunks of 2 rows
    int c = w * 2 + q;
    int row = c * 2 + (lane >> 5);
    gl_lds16(wsrc + (size_t)row * On + (lane & 31) * 4, wbuf[0] + c * 256);
  }
  bool act = list32[m * En + w * EW] >= 0;
  float2 acc[EW];
#pragma unroll
  for (int j = 0; j < EW; j++) acc[j] = make_float2(0.f, 0.f);
  __syncthreads();

  for (int t = 0; t < 16; t++) {
    if (t < 15) {
      const float* ws2 = wsrc + (size_t)(t + 1) * 16 * On;
#pragma unroll
      for (int q = 0; q < 2; q++) {
        int c = w * 2 + q;
        int row = c * 2 + (lane >> 5);
        gl_lds16(ws2 + (size_t)row * On + (lane & 31) * 4, wbuf[(t + 1) & 1] + c * 256);
      }
    }
    if (act) {
      const float* wb = wbuf[t & 1] + lane * 2;
      const float* xb = xbuf + (size_t)(t * 16) * En + w * EW;
#pragma unroll 8
      for (int k = 0; k < 16; k++) {
        float2 wv = *(const float2*)(wb + k * 128);
        float4 xa = *(const float4*)(xb + k * En);
        float4 xc = *(const float4*)(xb + k * En + 4);
        acc[0].x += xa.x * wv.x; acc[0].y += xa.x * wv.y;
        acc[1].x += xa.y * wv.x; acc[1].y += xa.y * wv.y;
        acc[2].x += xa.z * wv.x; acc[2].y += xa.z * wv.y;
        acc[3].x += xa.w * wv.x; acc[3].y += xa.w * wv.y;
        acc[4].x += xc.x * wv.x; acc[4].y += xc.x * wv.y;
        acc[5].x += xc.y * wv.x; acc[5].y += xc.y * wv.y;
        acc[6].x += xc.z * wv.x; acc[6].y += xc.z * wv.y;
        acc[7].x += xc.w * wv.x; acc[7].y += xc.w * wv.y;
      }
    }
    __syncthreads();
  }
  if (act) {
    float2 bv = *(const float2*)(bo + (size_t)m * On + ct * 128 + lane * 2);
    const float inv = 1.f / 7.f;
#pragma unroll
    for (int jj = 0; jj < EW; jj++) {
      int e = list32[m * En + w * EW + jj];
      if (e < 0) continue;
      float2 o;
      o.x = (acc[jj].x + bv.x) * inv;
      o.y = (acc[jj].y + bv.y) * inv;
      *(float2*)(comm_out + (size_t)e * On + ct * 128 + lane * 2) = o;
    }
  }
}

// -------- kernel 6: action softmax + baseline, 1 wave / example --------
__global__ __launch_bounds__(64) void k_act(
    const float* __restrict__ hid, const float* __restrict__ Wa,
    const float* __restrict__ ba, const float* __restrict__ Wb,
    const float* __restrict__ bb, const int* __restrict__ ids,
    float* __restrict__ aprob, float* __restrict__ bl) {
  int b = blockIdx.x;
  int m = ids[b];
  int l = threadIdx.x;
  int o = l & 15;
  int kk = l >> 4;

  const float* wap = Wa + (size_t)m * Hn * NACTn + l;
  const float* hbase = hid + (size_t)b * Hn;
  float al = 0.f;
  for (int w16 = 0; w16 < 4; w16++) {
    float wv[16], hv[16];
#pragma unroll
    for (int il = 0; il < 16; il++) wv[il] = wap[(w16 * 16 + il) * 64];
#pragma unroll
    for (int il = 0; il < 16; il++) hv[il] = hbase[w16 * 64 + il * 4 + kk];
#pragma unroll
    for (int il = 0; il < 16; il++) al += wv[il] * hv[il];
  }
  al += __shfl_xor(al, 16);
  al += __shfl_xor(al, 32);
  al += ba[m * NACTn + o];

  float mx = al;
  mx = fmaxf(mx, __shfl_xor(mx, 1));
  mx = fmaxf(mx, __shfl_xor(mx, 2));
  mx = fmaxf(mx, __shfl_xor(mx, 4));
  mx = fmaxf(mx, __shfl_xor(mx, 8));
  float ex = expf(al - mx);
  float sm = ex;
  sm += __shfl_xor(sm, 1);
  sm += __shfl_xor(sm, 2);
  sm += __shfl_xor(sm, 4);
  sm += __shfl_xor(sm, 8);
  if (l < 16) aprob[b * NACTn + l] = ex / sm;

  float pb = 0.f;
  const float* wbp = Wb + (size_t)m * Hn;
  {
    float wv[4], hv[4];
#pragma unroll
    for (int k = 0; k < 4; k++) { wv[k] = wbp[l + k * 64]; hv[k] = hbase[l + k * 64]; }
#pragma unroll
    for (int k = 0; k < 4; k++) pb += wv[k] * hv[k];
  }
  pb += __shfl_xor(pb, 1);
  pb += __shfl_xor(pb, 2);
  pb += __shfl_xor(pb, 4);
  pb += __shfl_xor(pb, 8);
  pb += __shfl_xor(pb, 16);
  pb += __shfl_xor(pb, 32);
  if (l == 0) bl[b] = pb + bb[m];
}

extern "C" void kernel_launch(void* const* d_in, const int* in_sizes, int n_in,
                              void* d_out, int out_size, void* d_ws, size_t ws_size,
                              hipStream_t stream) {
  const float* comm_in  = (const float*)d_in[0];
  const int*   inp      = (const int*)d_in[1];
  const float* prev_hid = (const float*)d_in[2];
  const int*   ids      = (const int*)d_in[4];
  const float* Wc = (const float*)d_in[5];
  const float* bc = (const float*)d_in[6];
  const float* Wr = (const float*)d_in[7];
  const float* br = (const float*)d_in[8];
  const float* Wa = (const float*)d_in[9];
  const float* ba = (const float*)d_in[10];
  const float* Wb = (const float*)d_in[11];
  const float* bb = (const float*)d_in[12];
  const float* Wo = (const float*)d_in[13];
  const float* bo = (const float*)d_in[14];
  const float* lut      = (const float*)d_in[15];
  const float* enc_bias = (const float*)d_in[16];

  float* out      = (float*)d_out;
  float* aprob    = out;                     // [512,16]
  float* bl       = out + Bn * NACTn;        // [512]
  float* hid      = out + Bn * NACTn + Bn;   // [512,256]
  float* comm_out = hid + Bn * Hn;           // [512,2048]

  char* ws = (char*)d_ws;
  int*   list32 = (int*)ws;                             // 4 KB
  float* xcat   = (float*)(ws + 4096);                  // [32][512][32] = 2 MB
  float* xh     = (float*)(ws + 4096 + 2097152);        // [32][256][32] = 1 MB
  float* acc4   = (float*)(ws + 4096 + 3145728);        // [4][32][32][256] = 4 MB

  k_group<<<1, 512, 0, stream>>>(ids, list32);
  k_pack<<<dim3(Mn, 2), 256, 0, stream>>>(comm_in, prev_hid, list32, xcat);
  k_lin<<<dim3(2, 4, Mn), 256, 0, stream>>>(Wc, Wr, xcat, list32, acc4);
  k_fin<<<dim3(Mn, 4), 256, 0, stream>>>(acc4, bc, br, inp, lut, enc_bias,
                                         list32, hid, xh);
  k_out<<<dim3(16, Mn), 256, 0, stream>>>(Wo, xh, bo, list32, comm_out);
  k_act<<<Bn, 64, 0, stream>>>(hid, Wa, ba, Wb, bb, ids, aprob, bl);
}

// Round 9
// 173.135 us; speedup vs baseline: 1.1691x; 1.1031x over previous
//
#include <hip/hip_runtime.h>

// CommNet forward, fp32. B=512, M=32, H=256, NAG=8, NACT=16.
// R9: 3-kernel pipeline (launch gaps dominate: R8 top-5 = harness 41us ws
// poison; kernels < 40us each). k_lin does in-block grouping + own x staging
// + DMA weight stream -> acc8 keyed BY EXAMPLE (decouples slot order across
// kernels). k_hidact = partial-sum + tanh + action/baseline. k_out = in-block
// grouping + hid->LDS transpose staging + DMA Wo stream.
// Kept lessons: DMA dest = wave-uniform base + lane*16B, chunk = 256 floats
// (R5 bug); >=2 co-resident blocks/CU for the vmcnt(0) drain (R7 collapse);
// no launch_bounds min-wave cap (R2 spill); no register streaming (R3/R4).

constexpr int Bn = 512, Mn = 32, NAGn = 8, Hn = 256, NACTn = 16;
constexpr int On = Hn * NAGn;  // 2048
constexpr int En = 32;         // padded slots/model (counts <= 32: held R1-R8)
constexpr int EW = 8;          // examples per wave
constexpr int XS = 40;         // x LDS stride: %4==0 (aligned b128), 4-way-only write conflicts

__device__ __forceinline__ void gl_lds16(const float* g, float* l) {
  __builtin_amdgcn_global_load_lds(
      (const __attribute__((address_space(1))) void*)g,
      (__attribute__((address_space(3))) void*)l, 16, 0, 0);
}

// build per-model example list in LDS (order nondeterministic; results keyed
// by example so order is irrelevant). All 256 threads must call.
__device__ __forceinline__ void build_group(const int* __restrict__ ids, int m,
                                            int* lst, int* cnt, int tid) {
  if (tid < En) lst[tid] = -1;
  if (tid == 0) *cnt = 0;
  __syncthreads();
  for (int i = tid; i < Bn; i += 256) {
    if (ids[i] == m) {
      int p = atomicAdd(cnt, 1);
      if (p < En) lst[p] = i;
    }
  }
  __syncthreads();
}

// ws: acc8 @0: [8 kc][512 e][256 col] f32 = 4 MB

// -------- kernel 1: acc8[kc][e][col] = x-chunk @ {Wc,Wr}-chunk --------------
// grid (2 ct[128col], 8 kc[64k: 0-3 Wc, 4-7 Wr], 32 m) = 512 blocks, 2/CU.
__global__ __launch_bounds__(256) void k_lin(
    const float* __restrict__ Wc, const float* __restrict__ Wr,
    const float* __restrict__ comm_in, const float* __restrict__ prev_hid,
    const int* __restrict__ ids, float* __restrict__ acc8) {
  int ct = blockIdx.x, kc = blockIdx.y, m = blockIdx.z;
  int tid = threadIdx.x, w = tid >> 6, lane = tid & 63;
  __shared__ int lst[En];
  __shared__ int cnt;
  __shared__ alignas(16) float xs[64 * XS];        // 10 KB
  __shared__ alignas(16) float wbuf[2][32 * 128];  // 32 KB

  build_group(ids, m, lst, &cnt, tid);
  if (cnt == 0) return;

  int kb = (kc & 3) * 64;
  const float* W = ((kc < 4) ? Wc : Wr) + (size_t)m * Hn * Hn + (size_t)kb * Hn + ct * 128;

  // stage x[k][j] (k local 0..63 = global kb+k); wave w stages its own octet.
  int k = lane, j0 = w * EW;
#pragma unroll
  for (int jj = 0; jj < EW; jj++) {
    int j = j0 + jj, e = lst[j];
    float v = 0.f;
    if (e >= 0) {
      if (kc < 4) {
        const float* cp = comm_in + (size_t)e * NAGn * Hn + kb + k;
#pragma unroll
        for (int a = 0; a < NAGn; a++) v += cp[a * Hn];
      } else {
        v = prev_hid[(size_t)e * Hn + kb + k];
      }
    }
    xs[k * XS + j] = v;
  }
  // DMA W tile 0 (rows 0..31): 16 chunks of 2 rows (256 floats)
#pragma unroll
  for (int q = 0; q < 4; q++) {
    int c = w * 4 + q;
    int row = c * 2 + (lane >> 5);
    gl_lds16(W + (size_t)row * Hn + (lane & 31) * 4, wbuf[0] + c * 256);
  }
  float2 acc[EW];
#pragma unroll
  for (int j = 0; j < EW; j++) acc[j] = make_float2(0.f, 0.f);
  __syncthreads();

  for (int t = 0; t < 2; t++) {
    if (t == 0) {
#pragma unroll
      for (int q = 0; q < 4; q++) {
        int c = w * 4 + q;
        int row = 32 + c * 2 + (lane >> 5);
        gl_lds16(W + (size_t)row * Hn + (lane & 31) * 4, wbuf[1] + c * 256);
      }
    }
    const float* wb = wbuf[t] + lane * 2;
    const float* xb = xs + (size_t)(t * 32) * XS + j0;
#pragma unroll 8
    for (int kk = 0; kk < 32; kk++) {
      float2 wv = *(const float2*)(wb + kk * 128);
      float4 xa = *(const float4*)(xb + kk * XS);
      float4 xc = *(const float4*)(xb + kk * XS + 4);
      acc[0].x += xa.x * wv.x; acc[0].y += xa.x * wv.y;
      acc[1].x += xa.y * wv.x; acc[1].y += xa.y * wv.y;
      acc[2].x += xa.z * wv.x; acc[2].y += xa.z * wv.y;
      acc[3].x += xa.w * wv.x; acc[3].y += xa.w * wv.y;
      acc[4].x += xc.x * wv.x; acc[4].y += xc.x * wv.y;
      acc[5].x += xc.y * wv.x; acc[5].y += xc.y * wv.y;
      acc[6].x += xc.z * wv.x; acc[6].y += xc.z * wv.y;
      acc[7].x += xc.w * wv.x; acc[7].y += xc.w * wv.y;
    }
    __syncthreads();
  }
#pragma unroll
  for (int jj = 0; jj < EW; jj++) {
    int e = lst[j0 + jj];
    if (e < 0) continue;
    *(float2*)(acc8 + ((size_t)kc * Bn + e) * Hn + ct * 128 + lane * 2) = acc[jj];
  }
}

// -------- kernel 2: hid = tanh(sum8 + biases); action softmax + baseline ----
// one block per example; 256 thr phase 1, wave 0 phase 2.
__global__ __launch_bounds__(256) void k_hidact(
    const float* __restrict__ acc8, const float* __restrict__ bc,
    const float* __restrict__ br, const int* __restrict__ inp,
    const float* __restrict__ lut, const float* __restrict__ enc_bias,
    const int* __restrict__ ids, const float* __restrict__ Wa,
    const float* __restrict__ ba, const float* __restrict__ Wb,
    const float* __restrict__ bb, float* __restrict__ hid,
    float* __restrict__ aprob, float* __restrict__ bl) {
  int e = blockIdx.x, tid = threadIdx.x;
  int m = ids[e];
  __shared__ float hs[Hn];
  float t = bc[m * Hn + tid] + br[m * Hn + tid] + enc_bias[tid] +
            lut[(size_t)inp[e] * Hn + tid];
#pragma unroll
  for (int kc = 0; kc < 8; kc++)
    t += acc8[((size_t)kc * Bn + e) * Hn + tid];
  float h = tanhf(t);
  hid[(size_t)e * Hn + tid] = h;
  hs[tid] = h;
  __syncthreads();
  if (tid < 64) {
    int l = tid, o = l & 15, kk = l >> 4;
    const float* wap = Wa + (size_t)m * Hn * NACTn + l;
    float al = 0.f;
    for (int w16 = 0; w16 < 4; w16++) {
      float wv[16], hv[16];
#pragma unroll
      for (int il = 0; il < 16; il++) wv[il] = wap[(w16 * 16 + il) * 64];
#pragma unroll
      for (int il = 0; il < 16; il++) hv[il] = hs[w16 * 64 + il * 4 + kk];
#pragma unroll
      for (int il = 0; il < 16; il++) al += wv[il] * hv[il];
    }
    al += __shfl_xor(al, 16);
    al += __shfl_xor(al, 32);
    al += ba[m * NACTn + o];

    float mx = al;
    mx = fmaxf(mx, __shfl_xor(mx, 1));
    mx = fmaxf(mx, __shfl_xor(mx, 2));
    mx = fmaxf(mx, __shfl_xor(mx, 4));
    mx = fmaxf(mx, __shfl_xor(mx, 8));
    float ex = expf(al - mx);
    float sm = ex;
    sm += __shfl_xor(sm, 1);
    sm += __shfl_xor(sm, 2);
    sm += __shfl_xor(sm, 4);
    sm += __shfl_xor(sm, 8);
    if (l < 16) aprob[e * NACTn + l] = ex / sm;

    float pb = 0.f;
    const float* wbp = Wb + (size_t)m * Hn;
    {
      float wv[4], hv[4];
#pragma unroll
      for (int k = 0; k < 4; k++) { wv[k] = wbp[l + k * 64]; hv[k] = hs[l + k * 64]; }
#pragma unroll
      for (int k = 0; k < 4; k++) pb += wv[k] * hv[k];
    }
    pb += __shfl_xor(pb, 1);
    pb += __shfl_xor(pb, 2);
    pb += __shfl_xor(pb, 4);
    pb += __shfl_xor(pb, 8);
    pb += __shfl_xor(pb, 16);
    pb += __shfl_xor(pb, 32);
    if (l == 0) bl[e] = pb + bb[m];
  }
}

// -------- kernel 3: comm_out = (hid @ Wo + bo) / 7, DMA-pipelined ----------
// grid (16 ct[128col], 32 m) = 512 blocks; 57KB LDS -> 2/CU. 16-row dbuf.
__global__ __launch_bounds__(256) void k_out(
    const float* __restrict__ Wo, const float* __restrict__ hid,
    const float* __restrict__ bo, const int* __restrict__ ids,
    float* __restrict__ comm_out) {
  int ct = blockIdx.x, m = blockIdx.y;
  int tid = threadIdx.x, w = tid >> 6, lane = tid & 63;
  __shared__ int lst[En];
  __shared__ int cnt;
  __shared__ alignas(16) float xs[Hn * XS];        // 40 KB
  __shared__ alignas(16) float wbuf[2][16 * 128];  // 16 KB

  build_group(ids, m, lst, &cnt, tid);
  if (cnt == 0) return;

  // stage x[k][j] from hid (manual transpose; tid = k)
  for (int j = 0; j < En; j++) {
    int e = lst[j];
    float v = (e >= 0) ? hid[(size_t)e * Hn + tid] : 0.f;
    xs[tid * XS + j] = v;
  }
  const float* wsrc = Wo + (size_t)m * Hn * On + ct * 128;
#pragma unroll
  for (int q = 0; q < 2; q++) {  // tile 0: rows 0..15; 8 chunks of 2 rows
    int c = w * 2 + q;
    int row = c * 2 + (lane >> 5);
    gl_lds16(wsrc + (size_t)row * On + (lane & 31) * 4, wbuf[0] + c * 256);
  }
  int j0 = w * EW;
  float2 acc[EW];
#pragma unroll
  for (int j = 0; j < EW; j++) acc[j] = make_float2(0.f, 0.f);
  __syncthreads();

  for (int t = 0; t < 16; t++) {
    if (t < 15) {
      const float* ws2 = wsrc + (size_t)(t + 1) * 16 * On;
#pragma unroll
      for (int q = 0; q < 2; q++) {
        int c = w * 2 + q;
        int row = c * 2 + (lane >> 5);
        gl_lds16(ws2 + (size_t)row * On + (lane & 31) * 4, wbuf[(t + 1) & 1] + c * 256);
      }
    }
    const float* wb = wbuf[t & 1] + lane * 2;
    const float* xb = xs + (size_t)(t * 16) * XS + j0;
#pragma unroll 8
    for (int k = 0; k < 16; k++) {
      float2 wv = *(const float2*)(wb + k * 128);
      float4 xa = *(const float4*)(xb + k * XS);
      float4 xc = *(const float4*)(xb + k * XS + 4);
      acc[0].x += xa.x * wv.x; acc[0].y += xa.x * wv.y;
      acc[1].x += xa.y * wv.x; acc[1].y += xa.y * wv.y;
      acc[2].x += xa.z * wv.x; acc[2].y += xa.z * wv.y;
      acc[3].x += xa.w * wv.x; acc[3].y += xa.w * wv.y;
      acc[4].x += xc.x * wv.x; acc[4].y += xc.x * wv.y;
      acc[5].x += xc.y * wv.x; acc[5].y += xc.y * wv.y;
      acc[6].x += xc.z * wv.x; acc[6].y += xc.z * wv.y;
      acc[7].x += xc.w * wv.x; acc[7].y += xc.w * wv.y;
    }
    __syncthreads();
  }
  float2 bv = *(const float2*)(bo + (size_t)m * On + ct * 128 + lane * 2);
  const float inv = 1.f / 7.f;
#pragma unroll
  for (int jj = 0; jj < EW; jj++) {
    int e = lst[j0 + jj];
    if (e < 0) continue;
    float2 o;
    o.x = (acc[jj].x + bv.x) * inv;
    o.y = (acc[jj].y + bv.y) * inv;
    *(float2*)(comm_out + (size_t)e * On + ct * 128 + lane * 2) = o;
  }
}

extern "C" void kernel_launch(void* const* d_in, const int* in_sizes, int n_in,
                              void* d_out, int out_size, void* d_ws, size_t ws_size,
                              hipStream_t stream) {
  const float* comm_in  = (const float*)d_in[0];
  const int*   inp      = (const int*)d_in[1];
  const float* prev_hid = (const float*)d_in[2];
  const int*   ids      = (const int*)d_in[4];
  const float* Wc = (const float*)d_in[5];
  const float* bc = (const float*)d_in[6];
  const float* Wr = (const float*)d_in[7];
  const float* br = (const float*)d_in[8];
  const float* Wa = (const float*)d_in[9];
  const float* ba = (const float*)d_in[10];
  const float* Wb = (const float*)d_in[11];
  const float* bb = (const float*)d_in[12];
  const float* Wo = (const float*)d_in[13];
  const float* bo = (const float*)d_in[14];
  const float* lut      = (const float*)d_in[15];
  const float* enc_bias = (const float*)d_in[16];

  float* out      = (float*)d_out;
  float* aprob    = out;                     // [512,16]
  float* bl       = out + Bn * NACTn;        // [512]
  float* hid      = out + Bn * NACTn + Bn;   // [512,256]
  float* comm_out = hid + Bn * Hn;           // [512,2048]

  float* acc8 = (float*)d_ws;                // [8][512][256] = 4 MB

  k_lin<<<dim3(2, 8, Mn), 256, 0, stream>>>(Wc, Wr, comm_in, prev_hid, ids, acc8);
  k_hidact<<<Bn, 256, 0, stream>>>(acc8, bc, br, inp, lut, enc_bias, ids,
                                   Wa, ba, Wb, bb, hid, aprob, bl);
  k_out<<<dim3(16, Mn), 256, 0, stream>>>(Wo, hid, bo, ids, comm_out);
}